// Round 4
// baseline (531.203 us; speedup 1.0000x reference)
//
#include <hip/hip_runtime.h>

#define T_SEQ 8192
#define E_DIM 1024
#define QS 36              // padded qkv row: [k 0..10][pad][q 12..22][pad][v 24..34][pad]
#define QNEC 16            // E-chunks in qkv projection
#define QKC 64             // cols per qkv chunk
#define QX4 16             // QKC/4 float4-cols
#define QXST 17            // f4 stride: 68 words = 4 mod 32 -> clean 4-word bank rotation
#define QRB 64             // qkv rows per block (1/lane), 26.6KB LDS -> 6 blocks/CU
#define AJC 64             // attn j-chunk rows
#define ARB 128            // attn rows per block (2/thread, 64-thread block)
#define KVW 24             // LDS kv row: [k0..10,pad][v0..10,pad]
#define TR 16              // pass2 rows per block

__device__ __forceinline__ float2 pkfma(float2 a, float2 b, float2 c) {
    return make_float2(fmaf(a.x, b.x, c.x), fmaf(a.y, b.y, c.y));
}
__device__ __forceinline__ float2 f2(float x, float y) { return make_float2(x, y); }

// ws floats: qkvF[T][QS] 1.18MB | wfp[E][12] 48KB | partQ[QNEC][T][QS] 18.9MB |
//   part1[T][12] 0.39MB (disjoint from partQ -> zeroed in prep before qkv_proj).
//   ~20.5MB total (< previous 26.4MB proven-safe footprint).

// ---------------------------------------------------------------------------
// K0: prep — pad Wf [E][11] -> [E][12] AND zero part1 (attn atomic accum dst)
// ---------------------------------------------------------------------------
__global__ __launch_bounds__(256) void prep(const float* __restrict__ Wf,
                                            float* __restrict__ Wfp,
                                            float* __restrict__ part1) {
    int id = blockIdx.x * 256 + threadIdx.x;
    if (id < E_DIM * 12) {
        int e = id / 12, d = id % 12;
        Wfp[id] = (d < 11) ? Wf[(size_t)e * 11 + d] : 0.f;
    } else {
        int j = id - E_DIM * 12;
        if (j < T_SEQ * 12) part1[j] = 0.f;
    }
}

// ---------------------------------------------------------------------------
// K1: qkv projection. Block 256 thr = 64 rows x 4 col-groups, 1 row/lane.
// LDS 26.6KB (xT 17.4 + wT 9.2) -> 6 blocks/CU (24 waves); grid 2048 blocks.
// Epilogue transposes through LDS, writes partQ as coalesced float4.
// ---------------------------------------------------------------------------
__global__ __launch_bounds__(256) void qkv_proj(
    const float* __restrict__ xe,
    const float* __restrict__ Wk, const float* __restrict__ bk,
    const float* __restrict__ Wq, const float* __restrict__ bq,
    const float* __restrict__ Wv, const float* __restrict__ bv,
    float* __restrict__ partQ) {
    const int row0 = blockIdx.x * QRB;
    const int ec = blockIdx.y;
    const int lane = threadIdx.x & 63;
    const int wg = threadIdx.x >> 6;
    const int cb = ec * QKC;

    __shared__ float4 xT[QRB * QXST];     // 17.4 KB
    __shared__ float4 wT[36 * QX4];       // 9.2 KB

    // stage xe tile: 1024 f4, 4/thread, 16 threads per 256B row (coalesced)
#pragma unroll
    for (int t = 0; t < 4; ++t) {
        int idx = threadIdx.x + t * 256;
        int r = idx >> 4, c4 = idx & 15;
        xT[r * QXST + c4] =
            *(const float4*)(xe + (size_t)(row0 + r) * E_DIM + cb + c4 * 4);
    }
    // stage W tile: 36 rows x 16 f4 (rows 33..35 zero)
    for (int idx = threadIdx.x; idx < 36 * QX4; idx += 256) {
        int r = idx >> 4, c4 = idx & 15;
        float4 v = make_float4(0.f, 0.f, 0.f, 0.f);
        if (r < 33) {
            const float* base = (r < 11) ? (Wk + (size_t)r * E_DIM)
                              : (r < 22) ? (Wq + (size_t)(r - 11) * E_DIM)
                                         : (Wv + (size_t)(r - 22) * E_DIM);
            v = *(const float4*)(base + cb + c4 * 4);
        }
        wT[idx] = v;
    }
    __syncthreads();

    float2 acc[9];
#pragma unroll
    for (int k = 0; k < 9; ++k) acc[k] = f2(0.f, 0.f);

    const float4* xr = xT + lane * QXST;
    const float4* wr = wT + wg * 9 * QX4;
#pragma unroll 4
    for (int c4 = 0; c4 < QX4; ++c4) {
        float4 xv = xr[c4];
#pragma unroll
        for (int k = 0; k < 9; ++k) {
            float4 wv = wr[k * QX4 + c4];          // broadcast
            acc[k] = pkfma(f2(xv.x, xv.y), f2(wv.x, wv.y), acc[k]);
            acc[k] = pkfma(f2(xv.z, xv.w), f2(wv.z, wv.w), acc[k]);
        }
    }

    // transpose through LDS (overlay on xT, dead after compute)
    __syncthreads();
    float* res = (float*)xT;                      // [64][36], 9.2KB
#pragma unroll
    for (int k = 0; k < 9; ++k) {
        int o = wg * 9 + k;
        bool live = (o < 33);
        int c = (o < 11) ? o : (o < 22) ? o + 1 : (o < 33) ? o + 2
              : (o == 33) ? 11 : (o == 34) ? 23 : 35;
        float b = 0.f;
        if (ec == 0 && live)
            b = (o < 11) ? bk[o] : (o < 22) ? bq[o - 11] : bv[o - 22];
        res[lane * 36 + c] = live ? (acc[k].x + acc[k].y + b) : 0.f;
    }
    __syncthreads();

    // coalesced f4 write: 64 rows x 9 f4 = 576 contiguous f4
    float4* dst = (float4*)(partQ + ((size_t)ec * T_SEQ + row0) * QS);
    for (int idx = threadIdx.x; idx < QRB * 9; idx += 256) {
        int r = idx / 9, f = idx % 9;
        dst[idx] = *(const float4*)(res + r * 36 + f * 4);
    }
}

// ---------------------------------------------------------------------------
// K2: reduce QNEC qkv partial chunks into dense qkvF.
// ---------------------------------------------------------------------------
__global__ __launch_bounds__(256) void reduceQ(const float* __restrict__ partQ,
                                               float* __restrict__ qkvF) {
    const size_t idx = (size_t)blockIdx.x * 256 + threadIdx.x;
    const float4* p = (const float4*)partQ;
    const size_t cs = (size_t)T_SEQ * (QS / 4);
    float4 s = make_float4(0.f, 0.f, 0.f, 0.f);
#pragma unroll
    for (int c = 0; c < QNEC; ++c) {
        float4 a = p[idx + (size_t)c * cs];
        s.x += a.x; s.y += a.y; s.z += a.z; s.w += a.w;
    }
    ((float4*)qkvF)[idx] = s;
}

// ---------------------------------------------------------------------------
// K3: causal attention, ONE-WAVE blocks (64 thr). Block b -> (rb, jc):
// prefix(rb) = rb(rb+1); jc in [0, 2rb+1]. Each block: 128 rows (2/lane) x
// ONE 64-j chunk -> 4160 uniform blocks (16/CU, ~4 waves/SIMD: 2x the old
// 2080-block latency hiding, half the work per block). 6KB LDS. Epilogue
// atomicAdd-accumulates 24 floats/lane into dense part1[T][12] (L2-resident)
// instead of 12.6MB of slotted partials.
// ---------------------------------------------------------------------------
__global__ __launch_bounds__(64) void attn(const float* __restrict__ qkvF,
                                           float* __restrict__ part1) {
    const int b = blockIdx.x;
    int rb = 0;
    while ((rb + 1) * (rb + 2) <= b) ++rb;        // prefix(rb) = rb(rb+1)
    const int jc = b - rb * (rb + 1);             // jc in [0, 2rb+1]
    const int lane = threadIdx.x;
    const int r0 = rb * ARB + lane * 2;
    const int j0 = jc * AJC;

    // q for 2 rows, packed as 6 f2 (pair 5 = (q10, 0))
    const float* qp0 = qkvF + (size_t)r0 * QS + 12;
    const float* qp1 = qp0 + QS;
    float2 qa[6], qb[6];
#pragma unroll
    for (int d = 0; d < 5; ++d) {
        qa[d] = f2(qp0[2 * d], qp0[2 * d + 1]);
        qb[d] = f2(qp1[2 * d], qp1[2 * d + 1]);
    }
    qa[5] = f2(qp0[10], 0.f);
    qb[5] = f2(qp1[10], 0.f);

    float2 oa[6], ob[6];
#pragma unroll
    for (int d = 0; d < 6; ++d) { oa[d] = f2(0.f, 0.f); ob[d] = f2(0.f, 0.f); }

    __shared__ float kv[AJC * KVW];               // 6 KB

    // stage 64 rows x 6 f4; 384 f4, 6 per lane
#pragma unroll
    for (int t = 0; t < 6; ++t) {
        int idx = lane + t * 64;
        int row = idx / 6, f = idx % 6;
        int srcOff = f * 4 + (f >= 3 ? 12 : 0);
        float4 v = *(const float4*)(qkvF + (size_t)(j0 + row) * QS + srcOff);
        *(float4*)(kv + row * KVW + f * 4) = v;
    }
    __syncthreads();

    for (int jj = 0; jj < AJC; ++jj) {
        const float* kp = kv + jj * KVW;
        const float4 kA = *(const float4*)(kp);
        const float4 kB = *(const float4*)(kp + 4);
        const float4 kC = *(const float4*)(kp + 8);   // .w = 0 (pad)
        const float4 vA = *(const float4*)(kp + 12);
        const float4 vB = *(const float4*)(kp + 16);
        const float4 vC = *(const float4*)(kp + 20);  // .w = 0 (pad)
        const float2 k01 = f2(kA.x, kA.y), k23 = f2(kA.z, kA.w);
        const float2 k45 = f2(kB.x, kB.y), k67 = f2(kB.z, kB.w);
        const float2 k89 = f2(kC.x, kC.y), kXp = f2(kC.z, kC.w);

        float2 sa = pkfma(qa[0], k01, pkfma(qa[1], k23, pkfma(qa[2], k45,
                    pkfma(qa[3], k67, pkfma(qa[4], k89,
                    pkfma(qa[5], kXp, f2(0.f, 0.f)))))));
        float2 sb = pkfma(qb[0], k01, pkfma(qb[1], k23, pkfma(qb[2], k45,
                    pkfma(qb[3], k67, pkfma(qb[4], k89,
                    pkfma(qb[5], kXp, f2(0.f, 0.f)))))));
        float pa = __expf(sa.x + sa.y);
        float pb = __expf(sb.x + sb.y);
        const int j = j0 + jj;
        pa = (j <= r0)     ? pa : 0.f;
        pb = (j <= r0 + 1) ? pb : 0.f;
        float2 pa2 = f2(pa, pa), pb2 = f2(pb, pb);
        oa[0] = pkfma(pa2, f2(vA.x, vA.y), oa[0]);
        oa[1] = pkfma(pa2, f2(vA.z, vA.w), oa[1]);
        oa[2] = pkfma(pa2, f2(vB.x, vB.y), oa[2]);
        oa[3] = pkfma(pa2, f2(vB.z, vB.w), oa[3]);
        oa[4] = pkfma(pa2, f2(vC.x, vC.y), oa[4]);
        oa[5] = pkfma(pa2, f2(vC.z, 1.f),  oa[5]);    // o10, l
        ob[0] = pkfma(pb2, f2(vA.x, vA.y), ob[0]);
        ob[1] = pkfma(pb2, f2(vA.z, vA.w), ob[1]);
        ob[2] = pkfma(pb2, f2(vB.x, vB.y), ob[2]);
        ob[3] = pkfma(pb2, f2(vB.z, vB.w), ob[3]);
        ob[4] = pkfma(pb2, f2(vC.x, vC.y), ob[4]);
        ob[5] = pkfma(pb2, f2(vC.z, 1.f),  ob[5]);
    }

    float* d0 = part1 + (size_t)r0 * 12;
    atomicAdd(d0 + 0,  oa[0].x); atomicAdd(d0 + 1,  oa[0].y);
    atomicAdd(d0 + 2,  oa[1].x); atomicAdd(d0 + 3,  oa[1].y);
    atomicAdd(d0 + 4,  oa[2].x); atomicAdd(d0 + 5,  oa[2].y);
    atomicAdd(d0 + 6,  oa[3].x); atomicAdd(d0 + 7,  oa[3].y);
    atomicAdd(d0 + 8,  oa[4].x); atomicAdd(d0 + 9,  oa[4].y);
    atomicAdd(d0 + 10, oa[5].x); atomicAdd(d0 + 11, oa[5].y);
    float* d1 = d0 + 12;
    atomicAdd(d1 + 0,  ob[0].x); atomicAdd(d1 + 1,  ob[0].y);
    atomicAdd(d1 + 2,  ob[1].x); atomicAdd(d1 + 3,  ob[1].y);
    atomicAdd(d1 + 4,  ob[2].x); atomicAdd(d1 + 5,  ob[2].y);
    atomicAdd(d1 + 6,  ob[3].x); atomicAdd(d1 + 7,  ob[3].y);
    atomicAdd(d1 + 8,  ob[4].x); atomicAdd(d1 + 9,  ob[4].y);
    atomicAdd(d1 + 10, ob[5].x); atomicAdd(d1 + 11, ob[5].y);
}

// ---------------------------------------------------------------------------
// K4: normalize + output GEMM + bias. part1 is fully reduced (cnt==1):
// one coalesced 768B load per block, then store-BW-bound GEMM epilogue.
// ---------------------------------------------------------------------------
__global__ __launch_bounds__(256) void pass2(const float* __restrict__ part1,
                                             const float* __restrict__ Wfp,
                                             const float* __restrict__ bf,
                                             float* __restrict__ out) {
    const int t0 = blockIdx.x * TR;
    __shared__ float res[TR][12];
    if (threadIdx.x < TR * 12) {
        float v = part1[(size_t)t0 * 12 + threadIdx.x];
        const int d = threadIdx.x % 12;
        res[threadIdx.x / 12][d] = (d == 11) ? (1.f / v) : v;
    }
    __syncthreads();

    const int e0 = threadIdx.x * 4;
    float4 wf[4][3];
#pragma unroll
    for (int ee = 0; ee < 4; ++ee) {
        const float4* wp = (const float4*)(Wfp + (size_t)(e0 + ee) * 12);
        wf[ee][0] = wp[0]; wf[ee][1] = wp[1]; wf[ee][2] = wp[2];
    }
    const float4 bv = *(const float4*)(bf + e0);

    for (int r = 0; r < TR; ++r) {
        float rr[12];
#pragma unroll
        for (int d = 0; d < 12; ++d) rr[d] = res[r][d];
        float2 a0 = f2(0.f, 0.f), a1 = a0, a2 = a0, a3 = a0;
#pragma unroll
        for (int d = 0; d < 10; d += 2) {
            float2 rv = f2(rr[d], rr[d + 1]);
            a0 = pkfma(rv, f2(((const float*)&wf[0][0])[d], ((const float*)&wf[0][0])[d + 1]), a0);
            a1 = pkfma(rv, f2(((const float*)&wf[1][0])[d], ((const float*)&wf[1][0])[d + 1]), a1);
            a2 = pkfma(rv, f2(((const float*)&wf[2][0])[d], ((const float*)&wf[2][0])[d + 1]), a2);
            a3 = pkfma(rv, f2(((const float*)&wf[3][0])[d], ((const float*)&wf[3][0])[d + 1]), a3);
        }
        const float rl = rr[11];
        float4 ov;
        ov.x = (a0.x + a0.y + rr[10] * wf[0][2].z) * rl + bv.x;
        ov.y = (a1.x + a1.y + rr[10] * wf[1][2].z) * rl + bv.y;
        ov.z = (a2.x + a2.y + rr[10] * wf[2][2].z) * rl + bv.z;
        ov.w = (a3.x + a3.y + rr[10] * wf[3][2].z) * rl + bv.w;
        *(float4*)(out + (size_t)(t0 + r) * E_DIM + e0) = ov;
    }
}

// ---------------------------------------------------------------------------
extern "C" void kernel_launch(void* const* d_in, const int* in_sizes, int n_in,
                              void* d_out, int out_size, void* d_ws, size_t ws_size,
                              hipStream_t stream) {
    const float* xe = (const float*)d_in[1];
    const float* Wk = (const float*)d_in[2];
    const float* bk = (const float*)d_in[3];
    const float* Wq = (const float*)d_in[4];
    const float* bq = (const float*)d_in[5];
    const float* Wv = (const float*)d_in[6];
    const float* bv = (const float*)d_in[7];
    const float* Wf = (const float*)d_in[8];
    const float* bf = (const float*)d_in[9];
    float* out = (float*)d_out;

    float* qkvF  = (float*)d_ws;                              // [T][QS]
    float* wfp   = qkvF + (size_t)T_SEQ * QS;                 // [E][12]
    float* partQ = wfp + (size_t)E_DIM * 12;                  // [QNEC][T][QS]
    float* part1 = partQ + (size_t)QNEC * T_SEQ * QS;         // [T][12] (disjoint)

    prep<<<(E_DIM * 12 + T_SEQ * 12 + 255) / 256, 256, 0, stream>>>(Wf, wfp, part1);
    qkv_proj<<<dim3(T_SEQ / QRB, QNEC), 256, 0, stream>>>(xe, Wk, bk, Wq, bq, Wv, bv, partQ);
    reduceQ<<<(T_SEQ * (QS / 4)) / 256, 256, 0, stream>>>(partQ, qkvF);
    const int nrb = T_SEQ / ARB;                              // 64
    attn<<<nrb * (nrb + 1), 64, 0, stream>>>(qkvF, part1);    // 4160 blocks
    pass2<<<T_SEQ / TR, 256, 0, stream>>>(part1, wfp, bf, out);
}

// Round 5
// 176.600 us; speedup vs baseline: 3.0079x; 3.0079x over previous
//
#include <hip/hip_runtime.h>

#define T_SEQ 8192
#define E_DIM 1024
#define QS 36              // padded qkv row: [k 0..10][pad][q 12..22][pad][v 24..34][pad]
#define QNEC 16            // E-chunks in qkv projection
#define QKC 64             // cols per qkv chunk
#define QX4 16             // QKC/4 float4-cols
#define QXST 17            // f4 stride: 68 words = 4 mod 32 -> clean 4-word bank rotation
#define QRB 64             // qkv rows per block (1/lane), 26.6KB LDS -> 6 blocks/CU
#define AJC 64             // attn j-chunk rows
#define ARB 128            // attn rows per row-group (2/lane per wave)
#define KVW 24             // LDS kv row: [k0..10,pad][v0..10,pad]
#define NSLOT 128          // attn partial slots (= max chunks for rb=63)
#define TR 16              // pass2 rows per block

__device__ __forceinline__ float2 pkfma(float2 a, float2 b, float2 c) {
    return make_float2(fmaf(a.x, b.x, c.x), fmaf(a.y, b.y, c.y));
}
__device__ __forceinline__ float2 f2(float x, float y) { return make_float2(x, y); }

// ws floats: qkvF[T][QS] 1.18MB | region R: partQ[QNEC][T][QS] 18.9MB overlaid
//   by part[128][T][12] 50.3MB (partQ dead after reduceQ; stream-ordered).
//   ~51.5MB total; ws is 256MB (harness fillBuffer = 262144KB). NO atomics:
//   R4 measured device-scope fp atomicAdd = ~32B HBM write-through each
//   (199.7MB WRITE_SIZE, 10x slowdown). Slot writes only.

// ---------------------------------------------------------------------------
// K1: qkv projection. Block 256 thr = 64 rows x 4 col-groups, 1 row/lane.
// LDS 26.6KB (xT 17.4 + wT 9.2) -> 6 blocks/CU (24 waves); grid 2048 blocks.
// Epilogue transposes through LDS, writes partQ as coalesced float4.
// ---------------------------------------------------------------------------
__global__ __launch_bounds__(256) void qkv_proj(
    const float* __restrict__ xe,
    const float* __restrict__ Wk, const float* __restrict__ bk,
    const float* __restrict__ Wq, const float* __restrict__ bq,
    const float* __restrict__ Wv, const float* __restrict__ bv,
    float* __restrict__ partQ) {
    const int row0 = blockIdx.x * QRB;
    const int ec = blockIdx.y;
    const int lane = threadIdx.x & 63;
    const int wg = threadIdx.x >> 6;
    const int cb = ec * QKC;

    __shared__ float4 xT[QRB * QXST];     // 17.4 KB
    __shared__ float4 wT[36 * QX4];       // 9.2 KB

    // stage xe tile: 1024 f4, 4/thread, 16 threads per 256B row (coalesced)
#pragma unroll
    for (int t = 0; t < 4; ++t) {
        int idx = threadIdx.x + t * 256;
        int r = idx >> 4, c4 = idx & 15;
        xT[r * QXST + c4] =
            *(const float4*)(xe + (size_t)(row0 + r) * E_DIM + cb + c4 * 4);
    }
    // stage W tile: 36 rows x 16 f4 (rows 33..35 zero)
    for (int idx = threadIdx.x; idx < 36 * QX4; idx += 256) {
        int r = idx >> 4, c4 = idx & 15;
        float4 v = make_float4(0.f, 0.f, 0.f, 0.f);
        if (r < 33) {
            const float* base = (r < 11) ? (Wk + (size_t)r * E_DIM)
                              : (r < 22) ? (Wq + (size_t)(r - 11) * E_DIM)
                                         : (Wv + (size_t)(r - 22) * E_DIM);
            v = *(const float4*)(base + cb + c4 * 4);
        }
        wT[idx] = v;
    }
    __syncthreads();

    float2 acc[9];
#pragma unroll
    for (int k = 0; k < 9; ++k) acc[k] = f2(0.f, 0.f);

    const float4* xr = xT + lane * QXST;
    const float4* wr = wT + wg * 9 * QX4;
#pragma unroll 4
    for (int c4 = 0; c4 < QX4; ++c4) {
        float4 xv = xr[c4];
#pragma unroll
        for (int k = 0; k < 9; ++k) {
            float4 wv = wr[k * QX4 + c4];          // broadcast
            acc[k] = pkfma(f2(xv.x, xv.y), f2(wv.x, wv.y), acc[k]);
            acc[k] = pkfma(f2(xv.z, xv.w), f2(wv.z, wv.w), acc[k]);
        }
    }

    // transpose through LDS (overlay on xT, dead after compute)
    __syncthreads();
    float* res = (float*)xT;                      // [64][36], 9.2KB
#pragma unroll
    for (int k = 0; k < 9; ++k) {
        int o = wg * 9 + k;
        bool live = (o < 33);
        int c = (o < 11) ? o : (o < 22) ? o + 1 : (o < 33) ? o + 2
              : (o == 33) ? 11 : (o == 34) ? 23 : 35;
        float b = 0.f;
        if (ec == 0 && live)
            b = (o < 11) ? bk[o] : (o < 22) ? bq[o - 11] : bv[o - 22];
        res[lane * 36 + c] = live ? (acc[k].x + acc[k].y + b) : 0.f;
    }
    __syncthreads();

    // coalesced f4 write: 64 rows x 9 f4 = 576 contiguous f4
    float4* dst = (float4*)(partQ + ((size_t)ec * T_SEQ + row0) * QS);
    for (int idx = threadIdx.x; idx < QRB * 9; idx += 256) {
        int r = idx / 9, f = idx % 9;
        dst[idx] = *(const float4*)(res + r * 36 + f * 4);
    }
}

// ---------------------------------------------------------------------------
// K2: reduce QNEC qkv partial chunks into dense qkvF.
// ---------------------------------------------------------------------------
__global__ __launch_bounds__(256) void reduceQ(const float* __restrict__ partQ,
                                               float* __restrict__ qkvF) {
    const size_t idx = (size_t)blockIdx.x * 256 + threadIdx.x;
    const float4* p = (const float4*)partQ;
    const size_t cs = (size_t)T_SEQ * (QS / 4);
    float4 s = make_float4(0.f, 0.f, 0.f, 0.f);
#pragma unroll
    for (int c = 0; c < QNEC; ++c) {
        float4 a = p[idx + (size_t)c * cs];
        s.x += a.x; s.y += a.y; s.z += a.z; s.w += a.w;
    }
    ((float4*)qkvF)[idx] = s;
}

// ---------------------------------------------------------------------------
// K3: causal attention, TWO-WAVE blocks (128 thr). Block b -> (rb, p):
// prefix(rb) = rb(rb+1)/2, p in [0, rb]. Wave w handles chunk jc = 2p+w
// (chunk count 2rb+2 is even -> always valid). 2080 blocks x 2 waves = 4160
// waves (~16 waves/CU), each: 128 rows (2/lane) x one 64-j chunk, private
// 6KB LDS half. Partials to slot jc of part[128][T][12] — plain coalesced
// stores, NO atomics (R4: fp atomicAdd = 32B HBM write-through, 10x cost).
// ---------------------------------------------------------------------------
__global__ __launch_bounds__(128) void attn(const float* __restrict__ qkvF,
                                            float* __restrict__ part) {
    const int b = blockIdx.x;
    int rb = 0;
    while ((rb + 1) * (rb + 2) / 2 <= b) ++rb;    // prefix(rb) = rb(rb+1)/2
    const int p = b - rb * (rb + 1) / 2;          // p in [0, rb]
    const int lane = threadIdx.x & 63;
    const int wid = threadIdx.x >> 6;
    const int jc = 2 * p + wid;                   // jc in [0, 2rb+1]
    const int r0 = rb * ARB + lane * 2;
    const int j0 = jc * AJC;

    // q for 2 rows, packed as 6 f2 (pair 5 = (q10, 0))
    const float* qp0 = qkvF + (size_t)r0 * QS + 12;
    const float* qp1 = qp0 + QS;
    float2 qa[6], qb[6];
#pragma unroll
    for (int d = 0; d < 5; ++d) {
        qa[d] = f2(qp0[2 * d], qp0[2 * d + 1]);
        qb[d] = f2(qp1[2 * d], qp1[2 * d + 1]);
    }
    qa[5] = f2(qp0[10], 0.f);
    qb[5] = f2(qp1[10], 0.f);

    float2 oa[6], ob[6];
#pragma unroll
    for (int d = 0; d < 6; ++d) { oa[d] = f2(0.f, 0.f); ob[d] = f2(0.f, 0.f); }

    __shared__ float kvs[2][AJC * KVW];           // 12 KB, one half per wave
    float* kv = kvs[wid];

    // stage 64 rows x 6 f4; 384 f4, 6 per lane (per wave, private chunk)
#pragma unroll
    for (int t = 0; t < 6; ++t) {
        int idx = lane + t * 64;
        int row = idx / 6, f = idx % 6;
        int srcOff = f * 4 + (f >= 3 ? 12 : 0);
        float4 v = *(const float4*)(qkvF + (size_t)(j0 + row) * QS + srcOff);
        *(float4*)(kv + row * KVW + f * 4) = v;
    }
    __syncthreads();

    for (int jj = 0; jj < AJC; ++jj) {
        const float* kp = kv + jj * KVW;
        const float4 kA = *(const float4*)(kp);
        const float4 kB = *(const float4*)(kp + 4);
        const float4 kC = *(const float4*)(kp + 8);   // .w = 0 (pad)
        const float4 vA = *(const float4*)(kp + 12);
        const float4 vB = *(const float4*)(kp + 16);
        const float4 vC = *(const float4*)(kp + 20);  // .w = 0 (pad)
        const float2 k01 = f2(kA.x, kA.y), k23 = f2(kA.z, kA.w);
        const float2 k45 = f2(kB.x, kB.y), k67 = f2(kB.z, kB.w);
        const float2 k89 = f2(kC.x, kC.y), kXp = f2(kC.z, kC.w);

        float2 sa = pkfma(qa[0], k01, pkfma(qa[1], k23, pkfma(qa[2], k45,
                    pkfma(qa[3], k67, pkfma(qa[4], k89,
                    pkfma(qa[5], kXp, f2(0.f, 0.f)))))));
        float2 sb = pkfma(qb[0], k01, pkfma(qb[1], k23, pkfma(qb[2], k45,
                    pkfma(qb[3], k67, pkfma(qb[4], k89,
                    pkfma(qb[5], kXp, f2(0.f, 0.f)))))));
        float pa = __expf(sa.x + sa.y);
        float pb = __expf(sb.x + sb.y);
        const int j = j0 + jj;
        pa = (j <= r0)     ? pa : 0.f;
        pb = (j <= r0 + 1) ? pb : 0.f;
        float2 pa2 = f2(pa, pa), pb2 = f2(pb, pb);
        oa[0] = pkfma(pa2, f2(vA.x, vA.y), oa[0]);
        oa[1] = pkfma(pa2, f2(vA.z, vA.w), oa[1]);
        oa[2] = pkfma(pa2, f2(vB.x, vB.y), oa[2]);
        oa[3] = pkfma(pa2, f2(vB.z, vB.w), oa[3]);
        oa[4] = pkfma(pa2, f2(vC.x, vC.y), oa[4]);
        oa[5] = pkfma(pa2, f2(vC.z, 1.f),  oa[5]);    // o10, l
        ob[0] = pkfma(pb2, f2(vA.x, vA.y), ob[0]);
        ob[1] = pkfma(pb2, f2(vA.z, vA.w), ob[1]);
        ob[2] = pkfma(pb2, f2(vB.x, vB.y), ob[2]);
        ob[3] = pkfma(pb2, f2(vB.z, vB.w), ob[3]);
        ob[4] = pkfma(pb2, f2(vC.x, vC.y), ob[4]);
        ob[5] = pkfma(pb2, f2(vC.z, 1.f),  ob[5]);
    }

    // slot write: contiguous 6KB per wave across 64 lanes
    float* d0 = part + ((size_t)jc * T_SEQ + r0) * 12;
    float4 t;
    t.x = oa[0].x; t.y = oa[0].y; t.z = oa[1].x; t.w = oa[1].y; *(float4*)(d0 + 0) = t;
    t.x = oa[2].x; t.y = oa[2].y; t.z = oa[3].x; t.w = oa[3].y; *(float4*)(d0 + 4) = t;
    t.x = oa[4].x; t.y = oa[4].y; t.z = oa[5].x; t.w = oa[5].y; *(float4*)(d0 + 8) = t;
    float* d1 = d0 + 12;
    t.x = ob[0].x; t.y = ob[0].y; t.z = ob[1].x; t.w = ob[1].y; *(float4*)(d1 + 0) = t;
    t.x = ob[2].x; t.y = ob[2].y; t.z = ob[3].x; t.w = ob[3].y; *(float4*)(d1 + 4) = t;
    t.x = ob[4].x; t.y = ob[4].y; t.z = ob[5].x; t.w = ob[5].y; *(float4*)(d1 + 8) = t;
}

// ---------------------------------------------------------------------------
// K4: fused partial-reduce + normalize + output GEMM + bias. Reads Wf
// directly (each thread: 4 contiguous 11-float rows, L3-resident) — prep
// kernel eliminated. Slot count for row t: 2*(t/128)+2 (even, <= 128).
// ---------------------------------------------------------------------------
__global__ __launch_bounds__(256) void pass2(const float* __restrict__ part,
                                             const float* __restrict__ Wf,
                                             const float* __restrict__ bf,
                                             float* __restrict__ out) {
    const int t0 = blockIdx.x * TR;
    __shared__ float res[TR][12];
    const int cnt = 2 * (t0 / ARB) + 2;           // uniform per block, even
    if (threadIdx.x < TR * 12) {
        const float* p = part + (size_t)t0 * 12 + threadIdx.x;
        const size_t S = (size_t)T_SEQ * 12;
        float v[4];
#pragma unroll
        for (int u = 0; u < 4; ++u) v[u] = 0.f;
        int c = 0;
        for (; c + 4 <= cnt; c += 4) {
#pragma unroll
            for (int u = 0; u < 4; ++u) v[u] += p[(size_t)(c + u) * S];
        }
        for (; c < cnt; ++c) v[0] += p[(size_t)c * S];
        float sum = (v[0] + v[1]) + (v[2] + v[3]);
        const int d = threadIdx.x % 12;
        res[threadIdx.x / 12][d] = (d == 11) ? (1.f / sum) : sum;
    }
    __syncthreads();

    const int e0 = threadIdx.x * 4;
    // direct Wf read: 4 rows x 11 floats = 176B contiguous per thread
    float w[4][11];
    const float* wp = Wf + (size_t)e0 * 11;
#pragma unroll
    for (int ee = 0; ee < 4; ++ee)
#pragma unroll
        for (int i = 0; i < 11; ++i) w[ee][i] = wp[ee * 11 + i];
    const float4 bv = *(const float4*)(bf + e0);

    for (int r = 0; r < TR; ++r) {
        float rr[12];
#pragma unroll
        for (int d = 0; d < 12; ++d) rr[d] = res[r][d];
        float2 a0 = f2(0.f, 0.f), a1 = a0, a2 = a0, a3 = a0;
#pragma unroll
        for (int d = 0; d < 10; d += 2) {
            float2 rv = f2(rr[d], rr[d + 1]);
            a0 = pkfma(rv, f2(w[0][d], w[0][d + 1]), a0);
            a1 = pkfma(rv, f2(w[1][d], w[1][d + 1]), a1);
            a2 = pkfma(rv, f2(w[2][d], w[2][d + 1]), a2);
            a3 = pkfma(rv, f2(w[3][d], w[3][d + 1]), a3);
        }
        const float rl = rr[11];
        float4 ov;
        ov.x = (a0.x + a0.y + rr[10] * w[0][10]) * rl + bv.x;
        ov.y = (a1.x + a1.y + rr[10] * w[1][10]) * rl + bv.y;
        ov.z = (a2.x + a2.y + rr[10] * w[2][10]) * rl + bv.z;
        ov.w = (a3.x + a3.y + rr[10] * w[3][10]) * rl + bv.w;
        *(float4*)(out + (size_t)(t0 + r) * E_DIM + e0) = ov;
    }
}

// ---------------------------------------------------------------------------
extern "C" void kernel_launch(void* const* d_in, const int* in_sizes, int n_in,
                              void* d_out, int out_size, void* d_ws, size_t ws_size,
                              hipStream_t stream) {
    const float* xe = (const float*)d_in[1];
    const float* Wk = (const float*)d_in[2];
    const float* bk = (const float*)d_in[3];
    const float* Wq = (const float*)d_in[4];
    const float* bq = (const float*)d_in[5];
    const float* Wv = (const float*)d_in[6];
    const float* bv = (const float*)d_in[7];
    const float* Wf = (const float*)d_in[8];
    const float* bf = (const float*)d_in[9];
    float* out = (float*)d_out;

    float* qkvF  = (float*)d_ws;                              // [T][QS]
    float* partQ = qkvF + (size_t)T_SEQ * QS;                 // [QNEC][T][QS]
    float* part  = partQ;                                     // overlay: [128][T][12]

    qkv_proj<<<dim3(T_SEQ / QRB, QNEC), 256, 0, stream>>>(xe, Wk, bk, Wq, bq, Wv, bv, partQ);
    reduceQ<<<(T_SEQ * (QS / 4)) / 256, 256, 0, stream>>>(partQ, qkvF);
    const int nrb = T_SEQ / ARB;                              // 64
    attn<<<nrb * (nrb + 1) / 2, 128, 0, stream>>>(qkvF, part); // 2080 blocks x 2 waves
    pass2<<<T_SEQ / TR, 256, 0, stream>>>(part, Wf, bf, out);
}